// Round 5
// baseline (744.912 us; speedup 1.0000x reference)
//
#include <hip/hip_runtime.h>
#include <stdint.h>

// Problem constants (fixed by the reference)
#define B_DIM 4
#define S_DIM 2048
#define DIN   4096
#define DOUT  4096
#define M_TOT (B_DIM * S_DIM)   // 8192

typedef __attribute__((ext_vector_type(8))) short  bf16x8;  // 8 bf16 = 4 VGPRs
typedef __attribute__((ext_vector_type(4))) float  f32x4;   // 4 fp32 acc
typedef __attribute__((ext_vector_type(4))) unsigned short u16x4;   // 8 B
typedef __attribute__((ext_vector_type(4))) float  float4v;

__device__ __forceinline__ unsigned short f2b(float f) {
  // round-to-nearest-even bf16
  union { float f; unsigned int i; } v; v.f = f;
  unsigned int r = v.i + 0x7FFFu + ((v.i >> 16) & 1u);
  return (unsigned short)(r >> 16);
}

// ---------------------------------------------------------------------------
// Fused convert kernel (unchanged — canonical coalescing, verified R3/R4).
//   blocks [0,2048):    wb = bf16( aa * tanh(kk * w) )
//   blocks [2048,6144): xb = bf16(x)
// ---------------------------------------------------------------------------
__global__ void cvt_fused_kernel(const float4v* __restrict__ w, u16x4* __restrict__ wbo,
                                 const float4v* __restrict__ x, u16x4* __restrict__ xbo,
                                 const float* __restrict__ kk,
                                 const float* __restrict__ aa) {
  const int bid = blockIdx.x;
  if (bid < 2048) {
    const float k = kk[0];
    const float a = aa[0];
    const int n4 = DOUT * DIN / 4;             // 4,194,304
    for (int i = bid * 256 + threadIdx.x; i < n4; i += 2048 * 256) {
      float4v v = w[i];
      u16x4 o;
#pragma unroll
      for (int j = 0; j < 4; ++j) o[j] = f2b(a * tanhf(k * v[j]));
      wbo[i] = o;
    }
  } else {
    const int n4 = M_TOT * DIN / 4;            // 8,388,608
    for (int i = (bid - 2048) * 256 + threadIdx.x; i < n4; i += 4096 * 256) {
      float4v v = x[i];
      u16x4 o;
#pragma unroll
      for (int j = 0; j < 4; ++j) o[j] = f2b(v[j]);
      xbo[i] = o;
    }
  }
}

// ---------------------------------------------------------------------------
// Kernel 3: 256x256 GEMM — R5: fragment READ-AHEAD + counted lgkmcnt gates +
// minimal barriers (3 per K-tile instead of 8).
//   Phase p issues the ds_reads for phase p+1, then MFMAs phase p: LDS drain
//   overlaps MFMA (was serialized in front of every cluster => 49% MfmaUtil).
//   DS ops complete in-order, so counted lgkm gates are exact:
//     P1 gate lgkm(4)  [forces prev-P4's 8 cross-tile reads done]
//     P2 gate lgkm(8)  [forces P1's 4]   P3 gate lgkm(4) [P2's 8]
//     P4 gate lgkm(8)  [P3's 4]
//   sched_barrier(0) after each gate (rule #18: MFMA hoists past asm waits).
//   Barrier/stage ledger (only 3 barriers load-bearing):
//     buf.A last read-issue @P3, completes by P4's gate  -> (t+2).A @ (t+1).P1
//       (after P4-close). buf.B last read-issue @P2, completes by P3's gate
//       -> (t+2).B @ t.P4 (after P3-close).
//     Cross-tile reads of (t+1) @ t.P4 come after P4-open-BAR; every wave
//       does vmcnt(4) BEFORE that barrier (12 outstanding: (t+1).B@(t-1).P4,
//       (t+1).A@t.P1, (t+2).B@t.P4 -> forces oldest 8 = all of tile t+1).
//   Per-acc accumulation order unchanged (acc0-3: ks0@P1,ks1@P3; acc4-7:
//   ks0@P2,ks1@P4) => bitwise-identical to R4.
// ---------------------------------------------------------------------------
#define BM 256
#define BN 256
#define BK 64
#define NT (DIN / BK)   // 64 K-tiles

__device__ __forceinline__ void glds16(const unsigned short* g, unsigned short* l) {
  __builtin_amdgcn_global_load_lds(
      (const __attribute__((address_space(1))) void*)g,
      (__attribute__((address_space(3))) void*)l,
      16, 0, 0);
}

#define BARX()    __builtin_amdgcn_s_barrier()
#define SB0()     __builtin_amdgcn_sched_barrier(0)
#define LGKMW(n)  asm volatile("s_waitcnt lgkmcnt(" #n ")" ::: "memory")
#define WAITVM4() asm volatile("s_waitcnt vmcnt(4)" ::: "memory")
#define WAITVM0() asm volatile("s_waitcnt vmcnt(0)" ::: "memory")

// B fragments: 4 x ds_read_b128 at one ks (BLK selects ks0/ks1 block set)
#define RDB(dst, BLK, BUFB)                                                   \
  dst[0] = *(const bf16x8*)(bRd + (BUFB) + 0 * 2048 + (BLK));                 \
  dst[1] = *(const bf16x8*)(bRd + (BUFB) + 1 * 2048 + (BLK));                 \
  dst[2] = *(const bf16x8*)(bRd + (BUFB) + 2 * 2048 + (BLK));                 \
  dst[3] = *(const bf16x8*)(bRd + (BUFB) + 3 * 2048 + (BLK));

// A fragments: 4 x ds_read_b128, mi = MB..MB+3 at one ks
#define RDA4(dst, MB, BLK, BUFB)                                              \
  dst[0] = *(const bf16x8*)(aRd + (BUFB) + ((MB) + 0) * 2048 + (BLK));        \
  dst[1] = *(const bf16x8*)(aRd + (BUFB) + ((MB) + 1) * 2048 + (BLK));        \
  dst[2] = *(const bf16x8*)(aRd + (BUFB) + ((MB) + 2) * 2048 + (BLK));        \
  dst[3] = *(const bf16x8*)(aRd + (BUFB) + ((MB) + 3) * 2048 + (BLK));

// one phase's MFMA cluster: 4 mi x 4 ni at one ks = 16 MFMA, setprio-wrapped
#define MFMA_PH(AF, BF, MB)                                                   \
  __builtin_amdgcn_s_setprio(1);                                              \
  {                                                                           \
    _Pragma("unroll")                                                         \
    for (int i = 0; i < 4; ++i)                                               \
      _Pragma("unroll")                                                       \
      for (int ni = 0; ni < 4; ++ni)                                          \
        acc[(MB) + i][ni] = __builtin_amdgcn_mfma_f32_16x16x32_bf16(          \
            AF[i], BF[ni], acc[(MB) + i][ni], 0, 0, 0);                       \
  }                                                                           \
  __builtin_amdgcn_s_setprio(0);

#define KTILE(t, BUFB, NBUFB)                                                 \
  {                                                                           \
    /* P1: stage (t+1).A; issue P2 frags; gate on prev-P4's cross reads */    \
    stageAh((t) + 1, 0); stageAh((t) + 1, 1);                                 \
    RDA4(afB, 4, blk0, BUFB);                                                 \
    LGKMW(4); SB0();                                                          \
    MFMA_PH(afA, bfr0, 0);                                                    \
    /* P2: issue P3 frags; gate on P1's */                                    \
    RDA4(afA, 0, blk1, BUFB);                                                 \
    RDB(bfr1, blk1, BUFB);                                                    \
    LGKMW(8); SB0();                                                          \
    MFMA_PH(afB, bfr0, 4);                                                    \
    /* P3: issue P4 frags; gate on P2's */                                    \
    RDA4(afB, 4, blk1, BUFB);                                                 \
    LGKMW(4); SB0();                                                          \
    MFMA_PH(afA, bfr1, 0);                                                    \
    BARX();  /* P3-close: all buf.B reads complete in every wave */           \
    /* P4: stage (t+2).B; all-wave vmcnt(4); cross-tile reads; gate P3's */   \
    stageBh((t) + 2, 0); stageBh((t) + 2, 1);                                 \
    if ((t) + 2 < NT) { WAITVM4(); } else { WAITVM0(); }                      \
    BARX();  /* P4-open: tile t+1 landed in every wave */                     \
    if ((t) + 1 < NT) {                                                       \
      RDA4(afA, 0, blk0, NBUFB);                                              \
      RDB(bfr0, blk0, NBUFB);                                                 \
    }                                                                         \
    LGKMW(8); SB0();                                                          \
    MFMA_PH(afB, bfr1, 4);                                                    \
    BARX();  /* P4-close: buf.A reads complete before (t+2).A stage */        \
  }

__global__ __launch_bounds__(512, 2)
void gemm256_kernel(const unsigned short* __restrict__ A,    // [M_TOT, DIN] bf16 bits
                    const unsigned short* __restrict__ Bw,   // [DOUT, DIN] bf16 bits
                    const float* __restrict__ bias,          // [DOUT] fp32
                    float* __restrict__ C) {                 // [M_TOT, DOUT] fp32
  __shared__ unsigned short lds[2][2][BM * BK];  // [buf][A/B][256*64] = 128 KiB

  const int tid  = threadIdx.x;
  const int wv   = tid >> 6;     // wave 0..7
  const int lane = tid & 63;
  const int l15  = lane & 15;
  const int quad = lane >> 4;
  const int l7   = lane & 7;
  const int rlan = lane >> 3;

  // XCD-aware 2D chunking (verified R2: FETCH 540->198 MB). Grid 512 =
  // 32 m-tiles x 16 n-tiles; XCD (bid&7) owns an 8x8 tile chunk. Bijective.
  const int xcd = blockIdx.x & 7;
  const int idx = blockIdx.x >> 3;                  // 0..63 within XCD
  const int bm  = ((((xcd & 3) << 3) | (idx & 7)) << 8);
  const int bn  = ((((xcd >> 2) << 3) | (idx >> 3)) << 8);

  // Per-lane staging source (verified: LDS block b of row r holds global
  // block b ^ (r&7); glds dest linear => pre-swizzle the source).
  const unsigned short* aLane = A  + (size_t)(bm + wv * 16 + rlan) * DIN + ((l7 ^ rlan) << 3);
  const unsigned short* bLane = Bw + (size_t)(bn + wv * 16 + rlan) * DIN + ((l7 ^ rlan) << 3);

  auto stageAh = [&](int kt, int hr) {   // one A half-tile: 2 glds/thread
    if (kt >= NT) return;
    const unsigned short* ga = aLane + (size_t)hr * (128 * DIN) + (size_t)kt * BK;
    unsigned short* la = &lds[kt & 1][0][hr * (128 * BK) + wv * (16 * BK)];
    glds16(ga, la);
    glds16(ga + 8 * DIN, la + 8 * BK);
  };
  auto stageBh = [&](int kt, int hr) {   // one B half-tile: 2 glds/thread
    if (kt >= NT) return;
    const unsigned short* gb = bLane + (size_t)hr * (128 * DIN) + (size_t)kt * BK;
    unsigned short* lb = &lds[kt & 1][1][hr * (128 * BK) + wv * (16 * BK)];
    glds16(gb, lb);
    glds16(gb + 8 * DIN, lb + 8 * BK);
  };

  // Compute-side LDS bases (bytes). Wave reads its own A-half / B-half only.
  const int hA   = wv >> 2;        // A half (rows 0-127 / 128-255)
  const int hB   = (wv & 3) >> 1;  // B half
  const int wloc = wv & 1;         // 64-col block within B half
  const char* aRd = (const char*)&lds[0][0][0] + hA * 16384 + l15 * 128;
  const char* bRd = (const char*)&lds[0][1][0] + hB * 16384 + wloc * 8192 + l15 * 128;
  const int blk0 = ((0 + quad) ^ l7) * 16;   // ks=0: logical block quad
  const int blk1 = ((4 + quad) ^ l7) * 16;   // ks=1: logical block 4+quad

  f32x4  acc[8][4] = {};
  bf16x8 bfr0[4], bfr1[4], afA[4], afB[4];

  // Prologue: stage tile0 fully then tile1.B (issue order matters: vmcnt(4)
  // forces the oldest 8 = all of tile 0; tile1.B stays in flight). Then
  // pre-read t0.P1's fragments (steady state has them read at prev P4).
  stageBh(0, 0); stageBh(0, 1); stageAh(0, 0); stageAh(0, 1);
  stageBh(1, 0); stageBh(1, 1);
  WAITVM4();
  BARX();
  RDA4(afA, 0, blk0, 0);
  RDB(bfr0, blk0, 0);

#pragma unroll 1
  for (int t = 0; t < NT; t += 2) {
    KTILE(t, 0, 65536);
    KTILE(t + 1, 65536, 0);
  }

  // --- epilogue: bias add + fp32 store (C/D map: col=lane&15, row=quad*4+e) ---
  const int wm = (wv >> 2) * 128;
  const int wn = (wv & 3) * 64;
#pragma unroll
  for (int ni = 0; ni < 4; ++ni) {
    const int col = bn + wn + ni * 16 + l15;
    const float bv = bias[col];
#pragma unroll
    for (int mi = 0; mi < 8; ++mi) {
      const int row0 = bm + wm + mi * 16 + quad * 4;
#pragma unroll
      for (int e = 0; e < 4; ++e)
        C[(size_t)(row0 + e) * DOUT + col] = acc[mi][ni][e] + bv;
    }
  }
}

// ---------------------------------------------------------------------------
extern "C" void kernel_launch(void* const* d_in, const int* in_sizes, int n_in,
                              void* d_out, int out_size, void* d_ws, size_t ws_size,
                              hipStream_t stream) {
  // setup_inputs order: x, weight, bias, kk, aa (fp32); OUTPUT fp32
  const float* x    = (const float*)d_in[0];  // [8192, 4096] fp32
  const float* w    = (const float*)d_in[1];  // [4096, 4096] fp32
  const float* bias = (const float*)d_in[2];  // [4096] fp32
  const float* kk   = (const float*)d_in[3];  // [1] fp32
  const float* aa   = (const float*)d_in[4];  // [1] fp32
  float* out = (float*)d_out;                 // [8192, 4096] fp32

  // ws layout: wb bf16 [4096,4096] at 0 (32 MB), xb bf16 [8192,4096] at +32MB
  unsigned short* wb = (unsigned short*)d_ws;
  unsigned short* xb = wb + (size_t)DOUT * DIN;

  cvt_fused_kernel<<<6144, 256, 0, stream>>>(
      (const float4v*)w, (u16x4*)wb, (const float4v*)x, (u16x4*)xb, kk, aa);

  // 512 blocks (32 m-tiles x 16 n-tiles), 512 threads, 1 block/CU (128 KiB LDS)
  gemm256_kernel<<<dim3(512), dim3(512), 0, stream>>>(xb, wb, bias, out);
}